// Round 14
// baseline (238.855 us; speedup 1.0000x reference)
//
#include <hip/hip_runtime.h>

typedef unsigned short u16;
typedef unsigned int u32;
using bf16x8 = __attribute__((ext_vector_type(8))) short;
using f32x4  = __attribute__((ext_vector_type(4))) float;
using ushort8 = __attribute__((ext_vector_type(8))) unsigned short;

__device__ __forceinline__ u16 f2bf(float f) {
  u32 u = __float_as_uint(f);
  return (u16)((u + 0x7FFFu + ((u >> 16) & 1u)) >> 16);
}
__device__ __forceinline__ float bf2f(u16 h) {
  return __uint_as_float(((u32)h) << 16);
}
__device__ __forceinline__ ushort8 umax8(ushort8 a, ushort8 b) {
  return __builtin_elementwise_max(a, b);
}
__device__ __forceinline__ void cvt_chunk(const float* __restrict__ in,
                                          u16* __restrict__ out, int i) {
  float4 v = ((const float4*)in)[i];
  uint2 o;
  o.x = (u32)f2bf(v.x) | ((u32)f2bf(v.y) << 16);
  o.y = (u32)f2bf(v.z) | ((u32)f2bf(v.w) << 16);
  ((uint2*)out)[i] = o;
}

// ---------------- fused conv3x3(3->64)+ReLU + vertical 4-row max -> M1 -------
// 1536 blocks: bid%3==2 -> fc1_w fp32->bf16 converter; else conv+vmax worker.
__global__ __launch_bounds__(512) void conv_vmax_k(
    const float* __restrict__ img, const float* __restrict__ w,
    const float* __restrict__ bias, u16* __restrict__ M1,
    const float* __restrict__ w1f, u16* __restrict__ w1b) {
  const int t = threadIdx.x;
  const int bid = blockIdx.x;
  const int r3 = bid % 3, q3 = bid / 3;
  if (r3 == 2) {  // converter: q3 in 0..511, n4 = 3211264
    int idx = q3 * 512 + t;
    for (int i = idx; i < 3211264; i += 262144) cvt_chunk(w1f, w1b, i);
    return;
  }
  const int widx = q3 * 2 + r3;  // 0..1023
  const int x = ((widx & 15) << 5) + (t >> 4);
  const int cq = (t & 15) << 2;
  const int y0 = (widx >> 4) << 3;

  float wr[27][4];
#pragma unroll
  for (int p = 0; p < 27; ++p)
#pragma unroll
    for (int c = 0; c < 4; ++c) wr[p][c] = w[(cq + c) * 27 + p];
  float bz[4];
#pragma unroll
  for (int c = 0; c < 4; ++c) bz[c] = bias[cq + c];

  const bool xm = (x > 0), xp = (x < 511);
  float win[3][3][3];

#define LOADROW(yy, s)                                                        \
  do {                                                                        \
    if ((yy) >= 0 && (yy) <= 511) {                                          \
      _Pragma("unroll") for (int ci = 0; ci < 3; ++ci) {                      \
        const float* rp = img + ci * 262144 + (yy) * 512 + x;                 \
        win[ci][s][0] = xm ? rp[-1] : 0.f;                                    \
        win[ci][s][1] = rp[0];                                                \
        win[ci][s][2] = xp ? rp[1] : 0.f;                                     \
      }                                                                        \
    } else {                                                                   \
      _Pragma("unroll") for (int ci = 0; ci < 3; ++ci) {                      \
        win[ci][s][0] = 0.f; win[ci][s][1] = 0.f; win[ci][s][2] = 0.f;        \
      }                                                                        \
    }                                                                          \
  } while (0)

  LOADROW(y0 - 1, 0);
  LOADROW(y0, 1);

  float h0[4], h1[4], h2[4], cur[4];
#pragma unroll
  for (int i = 0; i < 11; ++i) {
    const int r = y0 + i;
    LOADROW(r + 1, 2);
    if (r <= 511) {
#pragma unroll
      for (int c = 0; c < 4; ++c) cur[c] = bz[c];
#pragma unroll
      for (int ci = 0; ci < 3; ++ci)
#pragma unroll
        for (int ky = 0; ky < 3; ++ky)
#pragma unroll
          for (int kx = 0; kx < 3; ++kx) {
            const float iv = win[ci][ky][kx];
            const int p = ci * 9 + ky * 3 + kx;
#pragma unroll
            for (int c = 0; c < 4; ++c) cur[c] = fmaf(wr[p][c], iv, cur[c]);
          }
#pragma unroll
      for (int c = 0; c < 4; ++c) cur[c] = fmaxf(cur[c], 0.f);
    } else {
#pragma unroll
      for (int c = 0; c < 4; ++c) cur[c] = 0.f;
    }
    if (i >= 3) {
      const int ym = r - 3;
      float m[4];
#pragma unroll
      for (int c = 0; c < 4; ++c)
        m[c] = fmaxf(fmaxf(h0[c], h1[c]), fmaxf(h2[c], cur[c]));
      uint2 o;
      o.x = (u32)f2bf(m[0]) | ((u32)f2bf(m[1]) << 16);
      o.y = (u32)f2bf(m[2]) | ((u32)f2bf(m[3]) << 16);
      *(uint2*)(M1 + (((size_t)(ym * 512 + x)) << 6) + cq) = o;
    }
#pragma unroll
    for (int c = 0; c < 4; ++c) { h0[c] = h1[c]; h1[c] = h2[c]; h2[c] = cur[c]; }
#pragma unroll
    for (int ci = 0; ci < 3; ++ci)
#pragma unroll
      for (int kx = 0; kx < 3; ++kx) {
        win[ci][0][kx] = win[ci][1][kx];
        win[ci][1][kx] = win[ci][2][kx];
      }
  }
#undef LOADROW
}

// ---------------- RoI pool gather + interleaved fc2_w conversion -------------
__global__ __launch_bounds__(256) void roipool2_k(
    const u16* __restrict__ M1, const int* __restrict__ regions,
    u16* __restrict__ feat, const float* __restrict__ w2f,
    u16* __restrict__ w2b) {
  const int t = threadIdx.x;
  const int bid = blockIdx.x;
  const int r5 = bid % 5, q5 = bid / 5;
  if (r5 == 4) {  // converter: q5 in 0..511
    int idx = q5 * 256 + t;
    for (int i = idx; i < 4194304; i += 131072) cvt_chunk(w2f, w2b, i);
    return;
  }
  const int n = q5 * 4 + r5;  // 0..2047
  uint4* fdst = (uint4*)(feat + (size_t)n * 3136);
  if (n >= 2000) {
    uint4 z; z.x = z.y = z.z = z.w = 0u;
    for (int w = t; w < 392; w += 256) fdst[w] = z;
    return;
  }
  __shared__ u16 frow[3136];
  int r0 = regions[2 * n], c0 = regions[2 * n + 1];
  for (int w = t; w < 392; w += 256) {
    int bin = w >> 3, cg = w & 7;
    int py = bin / 7, px = bin % 7;
    int y = r0 + py * 4, xb = c0 + px * 4;
    const u16* base = M1 + (((size_t)(y * 512 + xb)) << 6) + cg * 8;
    ushort8 a = *(const ushort8*)(base);
    ushort8 b = *(const ushort8*)(base + 64);
    ushort8 c = *(const ushort8*)(base + 128);
    ushort8 d = *(const ushort8*)(base + 192);
    ushort8 m = umax8(umax8(a, b), umax8(c, d));
#pragma unroll
    for (int k = 0; k < 8; ++k) frow[(cg * 8 + k) * 49 + bin] = m[k];
  }
  __syncthreads();
  const uint4* fsrc = (const uint4*)frow;
  for (int w = t; w < 392; w += 256) fdst[w] = fsrc[w];
}

// ---------------- 4-wave split-K bf16 GEMM (B^T), 128x256 tile ---------------
// P[sk][m][n] (bf16) = sum_{k in half sk} A[m][k]*B[n][k].
// BM=128, BN=256, BK=32. 256 thr = 4 waves, wave wv owns cols [wv*64,+64):
// per-wave 128x64 output (8x4 fragments -> 384 B ds_read per MFMA).
// grid = 512 -> TWO independent blocks/CU (LDS 72KB x2 = 144 <= 160): the
// barrier-free overlap between blocks fills MFMA pipe during the other
// block's ds_read/staging phase (m114 mechanism; R13's 1-block/CU serialized).
// R7-proven minimal loop: {6 G2L(t+2); sched fence; 12 ds_read + 32 MFMA
// compiler-coscheduled; vmcnt(6); ONE barrier}.  3 LDS buffers.
// Swizzle (R3-verified, BK=32): LDS slot s holds global slot s^((r>>1)&3).
__global__ __launch_bounds__(256, 2) void gemm_sk4_k(
    const u16* __restrict__ A, const u16* __restrict__ B,
    u16* __restrict__ P, int K, int NT0, int NTtot) {
  __shared__ uint4 lds4[4608];  // 3 x (A 8KB | B 16KB) = 73728 B
  char* ldsb = (char*)lds4;
  const int t = threadIdx.x;
  const int lane = t & 63, wv = t >> 6;

  const int bid = blockIdx.x;            // grid must be exactly 512
  const int sk = bid & 1;                // adjacent blocks: different K-half
  const int q = bid >> 1;                // 0..255
  const int swz = ((q & 7) << 5) | (q >> 3);  // XCD-contiguous remap
  const int nb = swz >> 4, mb = swz & 15;
  const int m0 = mb * 128, n0 = nb * 256;
  const int ts = sk ? NT0 : 0;
  const int NTb = sk ? (NTtot - NT0) : NT0;

  const u16* __restrict__ Ab = A + (size_t)m0 * K;
  const u16* __restrict__ Bb = B + (size_t)n0 * K;
  const int srow = t >> 2;                      // 0..63 (sweep rows)
  const int sslot = (t & 3) ^ ((srow >> 1) & 3);
  const u16* pA0 = Ab + (size_t)srow * K + sslot * 8;
  const u16* pA1 = pA0 + (size_t)64 * K;
  const u16* pB0 = Bb + (size_t)srow * K + sslot * 8;
  const u16* pB1 = pB0 + (size_t)64 * K;
  const u16* pB2 = pB0 + (size_t)128 * K;
  const u16* pB3 = pB0 + (size_t)192 * K;
  const int dof = t * 16;

#define G2L(src, ldst)                                                        \
  __builtin_amdgcn_global_load_lds(                                          \
      (const __attribute__((address_space(1))) void*)(src),                  \
      (__attribute__((address_space(3))) void*)(ldst), 16, 0, 0)
#define LOFF(r, s) (((r) << 6) + ((((s) ^ (((r) >> 1) & 3))) << 4))
#define STAGE6(koff, buf)                                                     \
  do {                                                                        \
    G2L(pA0 + (koff), (buf) + dof);                                           \
    G2L(pA1 + (koff), (buf) + 4096 + dof);                                    \
    G2L(pB0 + (koff), (buf) + 8192 + dof);                                    \
    G2L(pB1 + (koff), (buf) + 12288 + dof);                                   \
    G2L(pB2 + (koff), (buf) + 16384 + dof);                                   \
    G2L(pB3 + (koff), (buf) + 20480 + dof);                                   \
  } while (0)

  const int row16 = lane & 15, sl = lane >> 4;
  f32x4 acc[8][4] = {};
  bf16x8 afr[8], bfr[4];

  // ---- prologue: stage tiles ts, ts+1
  {
    const size_t k0 = (size_t)ts * 32;
    STAGE6(k0, ldsb);
    if (NTb > 1) {
      STAGE6(k0 + 32, ldsb + 24576);
      asm volatile("s_waitcnt vmcnt(6)" ::: "memory");
    } else {
      asm volatile("s_waitcnt vmcnt(0)" ::: "memory");
    }
  }
  __builtin_amdgcn_s_barrier();

  int cb = 0;
  for (int tt = 0; tt < NTb; ++tt) {
    const int pb = (cb + 2 >= 3) ? cb - 1 : cb + 2;  // (tt+2)%3
    const bool pf = (tt + 2) < NTb;
    char* cbuf = ldsb + cb * 24576;
    if (pf) {
      char* fbuf = ldsb + pb * 24576;
      STAGE6((size_t)(ts + tt + 2) * 32, fbuf);
    }
    __builtin_amdgcn_sched_barrier(0);
    __builtin_amdgcn_s_setprio(1);
    char* Bc = cbuf + 8192;
#pragma unroll
    for (int j = 0; j < 4; ++j)
      bfr[j] = *(const bf16x8*)(Bc + LOFF(wv * 64 + j * 16 + row16, sl));
#pragma unroll
    for (int i = 0; i < 8; ++i)
      afr[i] = *(const bf16x8*)(cbuf + LOFF(i * 16 + row16, sl));
#pragma unroll
    for (int i = 0; i < 8; ++i)
#pragma unroll
      for (int j = 0; j < 4; ++j)
        acc[i][j] = __builtin_amdgcn_mfma_f32_16x16x32_bf16(afr[i], bfr[j], acc[i][j], 0, 0, 0);
    __builtin_amdgcn_s_setprio(0);
    if (pf) {
      asm volatile("s_waitcnt vmcnt(6)" ::: "memory");
    } else if (tt + 1 < NTb) {
      asm volatile("s_waitcnt vmcnt(0)" ::: "memory");
    }
    __builtin_amdgcn_s_barrier();
    cb = (cb == 2) ? 0 : cb + 1;
  }
#undef STAGE6
#undef G2L
#undef LOFF

  // ---- epilogue: bf16 partial store, P[sk][rg][cg], N fixed = 4096
  u16* Pb = P + (size_t)sk * 8388608;
#pragma unroll
  for (int i = 0; i < 8; ++i)
#pragma unroll
    for (int j = 0; j < 4; ++j) {
      const int cg = n0 + wv * 64 + j * 16 + row16;
#pragma unroll
      for (int r = 0; r < 4; ++r) {
        const int rg = m0 + i * 16 + sl * 4 + r;
        Pb[(size_t)rg * 4096 + cg] = f2bf(acc[i][j][r]);
      }
    }
}

// ---------------- finalize1: H = bf16(relu(P0+P1+bias[col])), 2048x4096 ------
__global__ __launch_bounds__(256) void finalize1_k(
    const u16* __restrict__ P, const float* __restrict__ bias,
    u16* __restrict__ H) {
  int c = blockIdx.x * 256 + threadIdx.x;  // 8-col chunk id, 1,048,576 total
  int row = c >> 9, c8 = (c & 511) << 3;
  size_t off = (size_t)row * 4096 + c8;
  ushort8 a = *(const ushort8*)(P + off);
  ushort8 b = *(const ushort8*)(P + 8388608 + off);
  float4 b0 = *(const float4*)(bias + c8);
  float4 b1 = *(const float4*)(bias + c8 + 4);
  float v[8];
#pragma unroll
  for (int e = 0; e < 8; ++e) v[e] = bf2f(a[e]) + bf2f(b[e]);
  v[0] += b0.x; v[1] += b0.y; v[2] += b0.z; v[3] += b0.w;
  v[4] += b1.x; v[5] += b1.y; v[6] += b1.z; v[7] += b1.w;
  uint4 o;
  o.x = (u32)f2bf(fmaxf(v[0], 0.f)) | ((u32)f2bf(fmaxf(v[1], 0.f)) << 16);
  o.y = (u32)f2bf(fmaxf(v[2], 0.f)) | ((u32)f2bf(fmaxf(v[3], 0.f)) << 16);
  o.z = (u32)f2bf(fmaxf(v[4], 0.f)) | ((u32)f2bf(fmaxf(v[5], 0.f)) << 16);
  o.w = (u32)f2bf(fmaxf(v[6], 0.f)) | ((u32)f2bf(fmaxf(v[7], 0.f)) << 16);
  *(uint4*)(H + off) = o;
}

// ---------------- heads2: fused fc2-finalize + cls/bbox heads ----------------
__global__ __launch_bounds__(256) void heads2_k(
    const u16* __restrict__ P, const float* __restrict__ bias,
    const float* __restrict__ cw, const float* __restrict__ cb,
    const float* __restrict__ bw, const float* __restrict__ bb,
    float* __restrict__ out) {
  __shared__ u16 wl[10][4096];  // 80 KB
  __shared__ float red[4][10];
  const int t = threadIdx.x;
  for (int i4 = t; i4 < 10240; i4 += 256) {
    int j = i4 >> 10, k4 = i4 & 1023;
    float4 v = (j < 2) ? ((const float4*)cw)[j * 1024 + k4]
                       : ((const float4*)bw)[(j - 2) * 1024 + k4];
    uint2 o;
    o.x = (u32)f2bf(v.x) | ((u32)f2bf(v.y) << 16);
    o.y = (u32)f2bf(v.z) | ((u32)f2bf(v.w) << 16);
    *(uint2*)(&wl[j][k4 * 4]) = o;
  }
  __syncthreads();
  const int lane = t & 63, wvi = t >> 6;
  const int m0 = blockIdx.x * 8;
  for (int mi = 0; mi < 8; ++mi) {
    const int m = m0 + mi;
    if (m >= 2000) break;
    const size_t roff = (size_t)m * 4096;
    float p[10];
#pragma unroll
    for (int j = 0; j < 10; ++j) p[j] = 0.f;
#pragma unroll
    for (int h = 0; h < 2; ++h) {
      const int kc = t + h * 256;
      const int c8 = kc * 8;
      ushort8 a = *(const ushort8*)(P + roff + c8);
      ushort8 b2 = *(const ushort8*)(P + 8388608 + roff + c8);
      float4 bi0 = *(const float4*)(bias + c8);
      float4 bi1 = *(const float4*)(bias + c8 + 4);
      float hf[8];
      hf[0] = fmaxf(bf2f(a[0]) + bf2f(b2[0]) + bi0.x, 0.f);
      hf[1] = fmaxf(bf2f(a[1]) + bf2f(b2[1]) + bi0.y, 0.f);
      hf[2] = fmaxf(bf2f(a[2]) + bf2f(b2[2]) + bi0.z, 0.f);
      hf[3] = fmaxf(bf2f(a[3]) + bf2f(b2[3]) + bi0.w, 0.f);
      hf[4] = fmaxf(bf2f(a[4]) + bf2f(b2[4]) + bi1.x, 0.f);
      hf[5] = fmaxf(bf2f(a[5]) + bf2f(b2[5]) + bi1.y, 0.f);
      hf[6] = fmaxf(bf2f(a[6]) + bf2f(b2[6]) + bi1.z, 0.f);
      hf[7] = fmaxf(bf2f(a[7]) + bf2f(b2[7]) + bi1.w, 0.f);
#pragma unroll
      for (int j = 0; j < 10; ++j) {
        ushort8 wvv = *(const ushort8*)(&wl[j][c8]);
#pragma unroll
        for (int e = 0; e < 8; ++e) p[j] = fmaf(hf[e], bf2f(wvv[e]), p[j]);
      }
    }
#pragma unroll
    for (int j = 0; j < 10; ++j)
#pragma unroll
      for (int off = 32; off > 0; off >>= 1) p[j] += __shfl_down(p[j], off);
    if (lane == 0) {
#pragma unroll
      for (int j = 0; j < 10; ++j) red[wvi][j] = p[j];
    }
    __syncthreads();
    if (t < 10) {
      float s = red[0][t] + red[1][t] + red[2][t] + red[3][t];
      s += (t < 2) ? cb[t] : bb[t - 2];
      if (t < 2) out[m * 2 + t] = s;
      else out[4000 + m * 8 + (t - 2)] = s;
    }
    __syncthreads();
  }
}

extern "C" void kernel_launch(void* const* d_in, const int* in_sizes, int n_in,
                              void* d_out, int out_size, void* d_ws, size_t ws_size,
                              hipStream_t stream) {
  const float* img    = (const float*)d_in[0];
  const int*   regions= (const int*)d_in[1];
  const float* conv_w = (const float*)d_in[2];
  const float* conv_b = (const float*)d_in[3];
  const float* fc1_w  = (const float*)d_in[4];
  const float* fc1_b  = (const float*)d_in[5];
  const float* fc2_w  = (const float*)d_in[6];
  const float* fc2_b  = (const float*)d_in[7];
  const float* cls_w  = (const float*)d_in[8];
  const float* cls_b  = (const float*)d_in[9];
  const float* bbox_w = (const float*)d_in[10];
  const float* bbox_b = (const float*)d_in[11];
  float* out = (float*)d_out;

  char* ws = (char*)d_ws;
  // layout (bytes), total 105,644,032:
  //   [0, 33554432)          M1 [512][512][64] bf16; dead after roipool2
  //                          -> P [2][2048][4096] bf16 (exactly 32 MiB)
  //   [33554432, 46399488)   feat [2048][3136] bf16 (dead after fc1 gemm)
  //   [46399488, 72089600)   w1b [4096][3136] bf16; dead after fc1 gemm
  //                          -> h1 [2048][4096] bf16 at 46399488 (16.8 MB)
  //   [72089600, 105644032)  w2b [4096][4096] bf16
  u16* M1   = (u16*)(ws);
  u16* P    = (u16*)(ws);
  u16* feat = (u16*)(ws + 33554432);
  u16* w1b  = (u16*)(ws + 46399488);
  u16* h1   = (u16*)(ws + 46399488);
  u16* w2b  = (u16*)(ws + 72089600);

  conv_vmax_k<<<1536, 512, 0, stream>>>(img, conv_w, conv_b, M1, fc1_w, w1b);
  roipool2_k<<<2560, 256, 0, stream>>>(M1, regions, feat, fc2_w, w2b);
  gemm_sk4_k<<<512, 256, 0, stream>>>(feat, w1b, P, 3136, 49, 98);
  finalize1_k<<<4096, 256, 0, stream>>>(P, fc1_b, h1);
  gemm_sk4_k<<<512, 256, 0, stream>>>(h1, w2b, P, 4096, 64, 128);
  heads2_k<<<250, 256, 0, stream>>>(P, fc2_b, cls_w, cls_b, bbox_w, bbox_b, out);
}

// Round 15
// 238.541 us; speedup vs baseline: 1.0013x; 1.0013x over previous
//
#include <hip/hip_runtime.h>

typedef unsigned short u16;
typedef unsigned int u32;
using bf16x8 = __attribute__((ext_vector_type(8))) short;
using f32x4  = __attribute__((ext_vector_type(4))) float;
using ushort8 = __attribute__((ext_vector_type(8))) unsigned short;

__device__ __forceinline__ u16 f2bf(float f) {
  u32 u = __float_as_uint(f);
  return (u16)((u + 0x7FFFu + ((u >> 16) & 1u)) >> 16);
}
__device__ __forceinline__ float bf2f(u16 h) {
  return __uint_as_float(((u32)h) << 16);
}
__device__ __forceinline__ ushort8 umax8(ushort8 a, ushort8 b) {
  return __builtin_elementwise_max(a, b);
}
__device__ __forceinline__ void cvt_chunk(const float* __restrict__ in,
                                          u16* __restrict__ out, int i) {
  float4 v = ((const float4*)in)[i];
  uint2 o;
  o.x = (u32)f2bf(v.x) | ((u32)f2bf(v.y) << 16);
  o.y = (u32)f2bf(v.z) | ((u32)f2bf(v.w) << 16);
  ((uint2*)out)[i] = o;
}

// ---------------- fused conv3x3(3->64)+ReLU + vertical 4-row max -> M1 -------
// 1536 blocks: bid%3==2 -> fc1_w fp32->bf16 converter; else conv+vmax worker.
__global__ __launch_bounds__(512) void conv_vmax_k(
    const float* __restrict__ img, const float* __restrict__ w,
    const float* __restrict__ bias, u16* __restrict__ M1,
    const float* __restrict__ w1f, u16* __restrict__ w1b) {
  const int t = threadIdx.x;
  const int bid = blockIdx.x;
  const int r3 = bid % 3, q3 = bid / 3;
  if (r3 == 2) {  // converter: q3 in 0..511, n4 = 3211264
    int idx = q3 * 512 + t;
    for (int i = idx; i < 3211264; i += 262144) cvt_chunk(w1f, w1b, i);
    return;
  }
  const int widx = q3 * 2 + r3;  // 0..1023
  const int x = ((widx & 15) << 5) + (t >> 4);
  const int cq = (t & 15) << 2;
  const int y0 = (widx >> 4) << 3;

  float wr[27][4];
#pragma unroll
  for (int p = 0; p < 27; ++p)
#pragma unroll
    for (int c = 0; c < 4; ++c) wr[p][c] = w[(cq + c) * 27 + p];
  float bz[4];
#pragma unroll
  for (int c = 0; c < 4; ++c) bz[c] = bias[cq + c];

  const bool xm = (x > 0), xp = (x < 511);
  float win[3][3][3];

#define LOADROW(yy, s)                                                        \
  do {                                                                        \
    if ((yy) >= 0 && (yy) <= 511) {                                          \
      _Pragma("unroll") for (int ci = 0; ci < 3; ++ci) {                      \
        const float* rp = img + ci * 262144 + (yy) * 512 + x;                 \
        win[ci][s][0] = xm ? rp[-1] : 0.f;                                    \
        win[ci][s][1] = rp[0];                                                \
        win[ci][s][2] = xp ? rp[1] : 0.f;                                     \
      }                                                                        \
    } else {                                                                   \
      _Pragma("unroll") for (int ci = 0; ci < 3; ++ci) {                      \
        win[ci][s][0] = 0.f; win[ci][s][1] = 0.f; win[ci][s][2] = 0.f;        \
      }                                                                        \
    }                                                                          \
  } while (0)

  LOADROW(y0 - 1, 0);
  LOADROW(y0, 1);

  float h0[4], h1[4], h2[4], cur[4];
#pragma unroll
  for (int i = 0; i < 11; ++i) {
    const int r = y0 + i;
    LOADROW(r + 1, 2);
    if (r <= 511) {
#pragma unroll
      for (int c = 0; c < 4; ++c) cur[c] = bz[c];
#pragma unroll
      for (int ci = 0; ci < 3; ++ci)
#pragma unroll
        for (int ky = 0; ky < 3; ++ky)
#pragma unroll
          for (int kx = 0; kx < 3; ++kx) {
            const float iv = win[ci][ky][kx];
            const int p = ci * 9 + ky * 3 + kx;
#pragma unroll
            for (int c = 0; c < 4; ++c) cur[c] = fmaf(wr[p][c], iv, cur[c]);
          }
#pragma unroll
      for (int c = 0; c < 4; ++c) cur[c] = fmaxf(cur[c], 0.f);
    } else {
#pragma unroll
      for (int c = 0; c < 4; ++c) cur[c] = 0.f;
    }
    if (i >= 3) {
      const int ym = r - 3;
      float m[4];
#pragma unroll
      for (int c = 0; c < 4; ++c)
        m[c] = fmaxf(fmaxf(h0[c], h1[c]), fmaxf(h2[c], cur[c]));
      uint2 o;
      o.x = (u32)f2bf(m[0]) | ((u32)f2bf(m[1]) << 16);
      o.y = (u32)f2bf(m[2]) | ((u32)f2bf(m[3]) << 16);
      *(uint2*)(M1 + (((size_t)(ym * 512 + x)) << 6) + cq) = o;
    }
#pragma unroll
    for (int c = 0; c < 4; ++c) { h0[c] = h1[c]; h1[c] = h2[c]; h2[c] = cur[c]; }
#pragma unroll
    for (int ci = 0; ci < 3; ++ci)
#pragma unroll
      for (int kx = 0; kx < 3; ++kx) {
        win[ci][0][kx] = win[ci][1][kx];
        win[ci][1][kx] = win[ci][2][kx];
      }
  }
#undef LOADROW
}

// ---------------- RoI pool gather + interleaved fc2_w conversion -------------
__global__ __launch_bounds__(256) void roipool2_k(
    const u16* __restrict__ M1, const int* __restrict__ regions,
    u16* __restrict__ feat, const float* __restrict__ w2f,
    u16* __restrict__ w2b) {
  const int t = threadIdx.x;
  const int bid = blockIdx.x;
  const int r5 = bid % 5, q5 = bid / 5;
  if (r5 == 4) {  // converter: q5 in 0..511
    int idx = q5 * 256 + t;
    for (int i = idx; i < 4194304; i += 131072) cvt_chunk(w2f, w2b, i);
    return;
  }
  const int n = q5 * 4 + r5;  // 0..2047
  uint4* fdst = (uint4*)(feat + (size_t)n * 3136);
  if (n >= 2000) {
    uint4 z; z.x = z.y = z.z = z.w = 0u;
    for (int w = t; w < 392; w += 256) fdst[w] = z;
    return;
  }
  __shared__ u16 frow[3136];
  int r0 = regions[2 * n], c0 = regions[2 * n + 1];
  for (int w = t; w < 392; w += 256) {
    int bin = w >> 3, cg = w & 7;
    int py = bin / 7, px = bin % 7;
    int y = r0 + py * 4, xb = c0 + px * 4;
    const u16* base = M1 + (((size_t)(y * 512 + xb)) << 6) + cg * 8;
    ushort8 a = *(const ushort8*)(base);
    ushort8 b = *(const ushort8*)(base + 64);
    ushort8 c = *(const ushort8*)(base + 128);
    ushort8 d = *(const ushort8*)(base + 192);
    ushort8 m = umax8(umax8(a, b), umax8(c, d));
#pragma unroll
    for (int k = 0; k < 8; ++k) frow[(cg * 8 + k) * 49 + bin] = m[k];
  }
  __syncthreads();
  const uint4* fsrc = (const uint4*)frow;
  for (int w = t; w < 392; w += 256) fdst[w] = fsrc[w];
}

// ---------------- 4-wave split-K bf16 GEMM (B^T), 128x256 tile ---------------
// P[sk][m][n] (bf16) = sum_{k in half sk} A[m][k]*B[n][k].
// BM=128, BN=256, BK=32. 256 thr = 4 waves, wave wv owns cols [wv*64,+64):
// per-wave 128x64 output (8x4 fragments -> 384 B ds_read per MFMA).
// grid = 512 -> TWO independent blocks/CU (LDS 72KB x2 = 144 <= 160): the
// barrier-free overlap between blocks fills MFMA pipe during the other
// block's ds_read/staging phase (m114 mechanism; R13's 1-block/CU serialized).
// R7-proven minimal loop: {6 G2L(t+2); sched fence; 12 ds_read + 32 MFMA
// compiler-coscheduled; vmcnt(6); ONE barrier}.  3 LDS buffers.
// Swizzle (R3-verified, BK=32): LDS slot s holds global slot s^((r>>1)&3).
__global__ __launch_bounds__(256, 2) void gemm_sk4_k(
    const u16* __restrict__ A, const u16* __restrict__ B,
    u16* __restrict__ P, int K, int NT0, int NTtot) {
  __shared__ uint4 lds4[4608];  // 3 x (A 8KB | B 16KB) = 73728 B
  char* ldsb = (char*)lds4;
  const int t = threadIdx.x;
  const int lane = t & 63, wv = t >> 6;

  const int bid = blockIdx.x;            // grid must be exactly 512
  const int sk = bid & 1;                // adjacent blocks: different K-half
  const int q = bid >> 1;                // 0..255
  const int swz = ((q & 7) << 5) | (q >> 3);  // XCD-contiguous remap
  const int nb = swz >> 4, mb = swz & 15;
  const int m0 = mb * 128, n0 = nb * 256;
  const int ts = sk ? NT0 : 0;
  const int NTb = sk ? (NTtot - NT0) : NT0;

  const u16* __restrict__ Ab = A + (size_t)m0 * K;
  const u16* __restrict__ Bb = B + (size_t)n0 * K;
  const int srow = t >> 2;                      // 0..63 (sweep rows)
  const int sslot = (t & 3) ^ ((srow >> 1) & 3);
  const u16* pA0 = Ab + (size_t)srow * K + sslot * 8;
  const u16* pA1 = pA0 + (size_t)64 * K;
  const u16* pB0 = Bb + (size_t)srow * K + sslot * 8;
  const u16* pB1 = pB0 + (size_t)64 * K;
  const u16* pB2 = pB0 + (size_t)128 * K;
  const u16* pB3 = pB0 + (size_t)192 * K;
  const int dof = t * 16;

#define G2L(src, ldst)                                                        \
  __builtin_amdgcn_global_load_lds(                                          \
      (const __attribute__((address_space(1))) void*)(src),                  \
      (__attribute__((address_space(3))) void*)(ldst), 16, 0, 0)
#define LOFF(r, s) (((r) << 6) + ((((s) ^ (((r) >> 1) & 3))) << 4))
#define STAGE6(koff, buf)                                                     \
  do {                                                                        \
    G2L(pA0 + (koff), (buf) + dof);                                           \
    G2L(pA1 + (koff), (buf) + 4096 + dof);                                    \
    G2L(pB0 + (koff), (buf) + 8192 + dof);                                    \
    G2L(pB1 + (koff), (buf) + 12288 + dof);                                   \
    G2L(pB2 + (koff), (buf) + 16384 + dof);                                   \
    G2L(pB3 + (koff), (buf) + 20480 + dof);                                   \
  } while (0)

  const int row16 = lane & 15, sl = lane >> 4;
  f32x4 acc[8][4] = {};
  bf16x8 afr[8], bfr[4];

  // ---- prologue: stage tiles ts, ts+1
  {
    const size_t k0 = (size_t)ts * 32;
    STAGE6(k0, ldsb);
    if (NTb > 1) {
      STAGE6(k0 + 32, ldsb + 24576);
      asm volatile("s_waitcnt vmcnt(6)" ::: "memory");
    } else {
      asm volatile("s_waitcnt vmcnt(0)" ::: "memory");
    }
  }
  __builtin_amdgcn_s_barrier();

  int cb = 0;
  for (int tt = 0; tt < NTb; ++tt) {
    const int pb = (cb + 2 >= 3) ? cb - 1 : cb + 2;  // (tt+2)%3
    const bool pf = (tt + 2) < NTb;
    char* cbuf = ldsb + cb * 24576;
    if (pf) {
      char* fbuf = ldsb + pb * 24576;
      STAGE6((size_t)(ts + tt + 2) * 32, fbuf);
    }
    __builtin_amdgcn_sched_barrier(0);
    __builtin_amdgcn_s_setprio(1);
    char* Bc = cbuf + 8192;
#pragma unroll
    for (int j = 0; j < 4; ++j)
      bfr[j] = *(const bf16x8*)(Bc + LOFF(wv * 64 + j * 16 + row16, sl));
#pragma unroll
    for (int i = 0; i < 8; ++i)
      afr[i] = *(const bf16x8*)(cbuf + LOFF(i * 16 + row16, sl));
#pragma unroll
    for (int i = 0; i < 8; ++i)
#pragma unroll
      for (int j = 0; j < 4; ++j)
        acc[i][j] = __builtin_amdgcn_mfma_f32_16x16x32_bf16(afr[i], bfr[j], acc[i][j], 0, 0, 0);
    __builtin_amdgcn_s_setprio(0);
    if (pf) {
      asm volatile("s_waitcnt vmcnt(6)" ::: "memory");
    } else if (tt + 1 < NTb) {
      asm volatile("s_waitcnt vmcnt(0)" ::: "memory");
    }
    __builtin_amdgcn_s_barrier();
    cb = (cb == 2) ? 0 : cb + 1;
  }
#undef STAGE6
#undef G2L
#undef LOFF

  // ---- epilogue: bf16 partial store, P[sk][rg][cg], N fixed = 4096
  u16* Pb = P + (size_t)sk * 8388608;
#pragma unroll
  for (int i = 0; i < 8; ++i)
#pragma unroll
    for (int j = 0; j < 4; ++j) {
      const int cg = n0 + wv * 64 + j * 16 + row16;
#pragma unroll
      for (int r = 0; r < 4; ++r) {
        const int rg = m0 + i * 16 + sl * 4 + r;
        Pb[(size_t)rg * 4096 + cg] = f2bf(acc[i][j][r]);
      }
    }
}

// ---------------- finalize1: H = bf16(relu(P0+P1+bias[col])), 2048x4096 ------
__global__ __launch_bounds__(256) void finalize1_k(
    const u16* __restrict__ P, const float* __restrict__ bias,
    u16* __restrict__ H) {
  int c = blockIdx.x * 256 + threadIdx.x;  // 8-col chunk id, 1,048,576 total
  int row = c >> 9, c8 = (c & 511) << 3;
  size_t off = (size_t)row * 4096 + c8;
  ushort8 a = *(const ushort8*)(P + off);
  ushort8 b = *(const ushort8*)(P + 8388608 + off);
  float4 b0 = *(const float4*)(bias + c8);
  float4 b1 = *(const float4*)(bias + c8 + 4);
  float v[8];
#pragma unroll
  for (int e = 0; e < 8; ++e) v[e] = bf2f(a[e]) + bf2f(b[e]);
  v[0] += b0.x; v[1] += b0.y; v[2] += b0.z; v[3] += b0.w;
  v[4] += b1.x; v[5] += b1.y; v[6] += b1.z; v[7] += b1.w;
  uint4 o;
  o.x = (u32)f2bf(fmaxf(v[0], 0.f)) | ((u32)f2bf(fmaxf(v[1], 0.f)) << 16);
  o.y = (u32)f2bf(fmaxf(v[2], 0.f)) | ((u32)f2bf(fmaxf(v[3], 0.f)) << 16);
  o.z = (u32)f2bf(fmaxf(v[4], 0.f)) | ((u32)f2bf(fmaxf(v[5], 0.f)) << 16);
  o.w = (u32)f2bf(fmaxf(v[6], 0.f)) | ((u32)f2bf(fmaxf(v[7], 0.f)) << 16);
  *(uint4*)(H + off) = o;
}

// ---------------- heads2: fused fc2-finalize + cls/bbox heads ----------------
__global__ __launch_bounds__(256) void heads2_k(
    const u16* __restrict__ P, const float* __restrict__ bias,
    const float* __restrict__ cw, const float* __restrict__ cb,
    const float* __restrict__ bw, const float* __restrict__ bb,
    float* __restrict__ out) {
  __shared__ u16 wl[10][4096];  // 80 KB
  __shared__ float red[4][10];
  const int t = threadIdx.x;
  for (int i4 = t; i4 < 10240; i4 += 256) {
    int j = i4 >> 10, k4 = i4 & 1023;
    float4 v = (j < 2) ? ((const float4*)cw)[j * 1024 + k4]
                       : ((const float4*)bw)[(j - 2) * 1024 + k4];
    uint2 o;
    o.x = (u32)f2bf(v.x) | ((u32)f2bf(v.y) << 16);
    o.y = (u32)f2bf(v.z) | ((u32)f2bf(v.w) << 16);
    *(uint2*)(&wl[j][k4 * 4]) = o;
  }
  __syncthreads();
  const int lane = t & 63, wvi = t >> 6;
  const int m0 = blockIdx.x * 8;
  for (int mi = 0; mi < 8; ++mi) {
    const int m = m0 + mi;
    if (m >= 2000) break;
    const size_t roff = (size_t)m * 4096;
    float p[10];
#pragma unroll
    for (int j = 0; j < 10; ++j) p[j] = 0.f;
#pragma unroll
    for (int h = 0; h < 2; ++h) {
      const int kc = t + h * 256;
      const int c8 = kc * 8;
      ushort8 a = *(const ushort8*)(P + roff + c8);
      ushort8 b2 = *(const ushort8*)(P + 8388608 + roff + c8);
      float4 bi0 = *(const float4*)(bias + c8);
      float4 bi1 = *(const float4*)(bias + c8 + 4);
      float hf[8];
      hf[0] = fmaxf(bf2f(a[0]) + bf2f(b2[0]) + bi0.x, 0.f);
      hf[1] = fmaxf(bf2f(a[1]) + bf2f(b2[1]) + bi0.y, 0.f);
      hf[2] = fmaxf(bf2f(a[2]) + bf2f(b2[2]) + bi0.z, 0.f);
      hf[3] = fmaxf(bf2f(a[3]) + bf2f(b2[3]) + bi0.w, 0.f);
      hf[4] = fmaxf(bf2f(a[4]) + bf2f(b2[4]) + bi1.x, 0.f);
      hf[5] = fmaxf(bf2f(a[5]) + bf2f(b2[5]) + bi1.y, 0.f);
      hf[6] = fmaxf(bf2f(a[6]) + bf2f(b2[6]) + bi1.z, 0.f);
      hf[7] = fmaxf(bf2f(a[7]) + bf2f(b2[7]) + bi1.w, 0.f);
#pragma unroll
      for (int j = 0; j < 10; ++j) {
        ushort8 wvv = *(const ushort8*)(&wl[j][c8]);
#pragma unroll
        for (int e = 0; e < 8; ++e) p[j] = fmaf(hf[e], bf2f(wvv[e]), p[j]);
      }
    }
#pragma unroll
    for (int j = 0; j < 10; ++j)
#pragma unroll
      for (int off = 32; off > 0; off >>= 1) p[j] += __shfl_down(p[j], off);
    if (lane == 0) {
#pragma unroll
      for (int j = 0; j < 10; ++j) red[wvi][j] = p[j];
    }
    __syncthreads();
    if (t < 10) {
      float s = red[0][t] + red[1][t] + red[2][t] + red[3][t];
      s += (t < 2) ? cb[t] : bb[t - 2];
      if (t < 2) out[m * 2 + t] = s;
      else out[4000 + m * 8 + (t - 2)] = s;
    }
    __syncthreads();
  }
}

extern "C" void kernel_launch(void* const* d_in, const int* in_sizes, int n_in,
                              void* d_out, int out_size, void* d_ws, size_t ws_size,
                              hipStream_t stream) {
  const float* img    = (const float*)d_in[0];
  const int*   regions= (const int*)d_in[1];
  const float* conv_w = (const float*)d_in[2];
  const float* conv_b = (const float*)d_in[3];
  const float* fc1_w  = (const float*)d_in[4];
  const float* fc1_b  = (const float*)d_in[5];
  const float* fc2_w  = (const float*)d_in[6];
  const float* fc2_b  = (const float*)d_in[7];
  const float* cls_w  = (const float*)d_in[8];
  const float* cls_b  = (const float*)d_in[9];
  const float* bbox_w = (const float*)d_in[10];
  const float* bbox_b = (const float*)d_in[11];
  float* out = (float*)d_out;

  char* ws = (char*)d_ws;
  // layout (bytes), total 105,644,032:
  //   [0, 33554432)          M1 [512][512][64] bf16; dead after roipool2
  //                          -> P [2][2048][4096] bf16 (exactly 32 MiB)
  //   [33554432, 46399488)   feat [2048][3136] bf16 (dead after fc1 gemm)
  //   [46399488, 72089600)   w1b [4096][3136] bf16; dead after fc1 gemm
  //                          -> h1 [2048][4096] bf16 at 46399488 (16.8 MB)
  //   [72089600, 105644032)  w2b [4096][4096] bf16
  u16* M1   = (u16*)(ws);
  u16* P    = (u16*)(ws);
  u16* feat = (u16*)(ws + 33554432);
  u16* w1b  = (u16*)(ws + 46399488);
  u16* h1   = (u16*)(ws + 46399488);
  u16* w2b  = (u16*)(ws + 72089600);

  conv_vmax_k<<<1536, 512, 0, stream>>>(img, conv_w, conv_b, M1, fc1_w, w1b);
  roipool2_k<<<2560, 256, 0, stream>>>(M1, regions, feat, fc2_w, w2b);
  gemm_sk4_k<<<512, 256, 0, stream>>>(feat, w1b, P, 3136, 49, 98);
  finalize1_k<<<4096, 256, 0, stream>>>(P, fc1_b, h1);
  gemm_sk4_k<<<512, 256, 0, stream>>>(h1, w2b, P, 4096, 64, 128);
  heads2_k<<<250, 256, 0, stream>>>(P, fc2_b, cls_w, cls_b, bbox_w, bbox_b, out);
}

// Round 16
// 218.863 us; speedup vs baseline: 1.0913x; 1.0899x over previous
//
#include <hip/hip_runtime.h>

typedef unsigned short u16;
typedef unsigned int u32;
using bf16x8 = __attribute__((ext_vector_type(8))) short;
using f32x4  = __attribute__((ext_vector_type(4))) float;
using ushort8 = __attribute__((ext_vector_type(8))) unsigned short;

__device__ __forceinline__ u16 f2bf(float f) {
  u32 u = __float_as_uint(f);
  return (u16)((u + 0x7FFFu + ((u >> 16) & 1u)) >> 16);
}
__device__ __forceinline__ float bf2f(u16 h) {
  return __uint_as_float(((u32)h) << 16);
}
__device__ __forceinline__ ushort8 umax8(ushort8 a, ushort8 b) {
  return __builtin_elementwise_max(a, b);
}
__device__ __forceinline__ void cvt_chunk(const float* __restrict__ in,
                                          u16* __restrict__ out, int i) {
  float4 v = ((const float4*)in)[i];
  uint2 o;
  o.x = (u32)f2bf(v.x) | ((u32)f2bf(v.y) << 16);
  o.y = (u32)f2bf(v.z) | ((u32)f2bf(v.w) << 16);
  ((uint2*)out)[i] = o;
}

// ---------------- fused conv3x3(3->64)+ReLU + vertical 4-row max -> M1 -------
// blocks 0..1023: conv+vmax.  blocks 1024..1535: fc1_w fp32->bf16 (w1b).
__global__ __launch_bounds__(512) void conv_vmax_k(
    const float* __restrict__ img, const float* __restrict__ w,
    const float* __restrict__ bias, u16* __restrict__ M1,
    const float* __restrict__ w1f, u16* __restrict__ w1b) {
  const int t = threadIdx.x;
  if (blockIdx.x >= 1024) {  // converter blocks: 512 x 512 thr, n4=3211264
    int idx = (blockIdx.x - 1024) * 512 + t;
    for (int i = idx; i < 3211264; i += 262144) cvt_chunk(w1f, w1b, i);
    return;
  }
  const int x = ((blockIdx.x & 15) << 5) + (t >> 4);
  const int cq = (t & 15) << 2;
  const int y0 = (blockIdx.x >> 4) << 3;

  float wr[27][4];
#pragma unroll
  for (int p = 0; p < 27; ++p)
#pragma unroll
    for (int c = 0; c < 4; ++c) wr[p][c] = w[(cq + c) * 27 + p];
  float bz[4];
#pragma unroll
  for (int c = 0; c < 4; ++c) bz[c] = bias[cq + c];

  const bool xm = (x > 0), xp = (x < 511);
  float win[3][3][3];

#define LOADROW(yy, s)                                                        \
  do {                                                                        \
    if ((yy) >= 0 && (yy) <= 511) {                                          \
      _Pragma("unroll") for (int ci = 0; ci < 3; ++ci) {                      \
        const float* rp = img + ci * 262144 + (yy) * 512 + x;                 \
        win[ci][s][0] = xm ? rp[-1] : 0.f;                                    \
        win[ci][s][1] = rp[0];                                                \
        win[ci][s][2] = xp ? rp[1] : 0.f;                                     \
      }                                                                        \
    } else {                                                                   \
      _Pragma("unroll") for (int ci = 0; ci < 3; ++ci) {                      \
        win[ci][s][0] = 0.f; win[ci][s][1] = 0.f; win[ci][s][2] = 0.f;        \
      }                                                                        \
    }                                                                          \
  } while (0)

  LOADROW(y0 - 1, 0);
  LOADROW(y0, 1);

  float h0[4], h1[4], h2[4], cur[4];
#pragma unroll
  for (int i = 0; i < 11; ++i) {
    const int r = y0 + i;
    LOADROW(r + 1, 2);
    if (r <= 511) {
#pragma unroll
      for (int c = 0; c < 4; ++c) cur[c] = bz[c];
#pragma unroll
      for (int ci = 0; ci < 3; ++ci)
#pragma unroll
        for (int ky = 0; ky < 3; ++ky)
#pragma unroll
          for (int kx = 0; kx < 3; ++kx) {
            const float iv = win[ci][ky][kx];
            const int p = ci * 9 + ky * 3 + kx;
#pragma unroll
            for (int c = 0; c < 4; ++c) cur[c] = fmaf(wr[p][c], iv, cur[c]);
          }
#pragma unroll
      for (int c = 0; c < 4; ++c) cur[c] = fmaxf(cur[c], 0.f);
    } else {
#pragma unroll
      for (int c = 0; c < 4; ++c) cur[c] = 0.f;
    }
    if (i >= 3) {
      const int ym = r - 3;
      float m[4];
#pragma unroll
      for (int c = 0; c < 4; ++c)
        m[c] = fmaxf(fmaxf(h0[c], h1[c]), fmaxf(h2[c], cur[c]));
      uint2 o;
      o.x = (u32)f2bf(m[0]) | ((u32)f2bf(m[1]) << 16);
      o.y = (u32)f2bf(m[2]) | ((u32)f2bf(m[3]) << 16);
      *(uint2*)(M1 + (((size_t)(ym * 512 + x)) << 6) + cq) = o;
    }
#pragma unroll
    for (int c = 0; c < 4; ++c) { h0[c] = h1[c]; h1[c] = h2[c]; h2[c] = cur[c]; }
#pragma unroll
    for (int ci = 0; ci < 3; ++ci)
#pragma unroll
      for (int kx = 0; kx < 3; ++kx) {
        win[ci][0][kx] = win[ci][1][kx];
        win[ci][1][kx] = win[ci][2][kx];
      }
  }
#undef LOADROW
}

// ---------------- RoI pool gather + co-launched fc2_w conversion -------------
// blocks 0..2047: pool (>=2000 zero-pad); blocks 2048..2559: fc2_w converter.
__global__ __launch_bounds__(256) void roipool2_k(
    const u16* __restrict__ M1, const int* __restrict__ regions,
    u16* __restrict__ feat, const float* __restrict__ w2f,
    u16* __restrict__ w2b) {
  int n = blockIdx.x, t = threadIdx.x;
  if (n >= 2048) {  // converter blocks: 512 x 256 thr
    int idx = (n - 2048) * 256 + t;
    for (int i = idx; i < 4194304; i += 131072) cvt_chunk(w2f, w2b, i);
    return;
  }
  uint4* fdst = (uint4*)(feat + (size_t)n * 3136);
  if (n >= 2000) {
    uint4 z; z.x = z.y = z.z = z.w = 0u;
    for (int w = t; w < 392; w += 256) fdst[w] = z;
    return;
  }
  __shared__ u16 frow[3136];
  int r0 = regions[2 * n], c0 = regions[2 * n + 1];
  for (int w = t; w < 392; w += 256) {
    int bin = w >> 3, cg = w & 7;
    int py = bin / 7, px = bin % 7;
    int y = r0 + py * 4, xb = c0 + px * 4;
    const u16* base = M1 + (((size_t)(y * 512 + xb)) << 6) + cg * 8;
    ushort8 a = *(const ushort8*)(base);
    ushort8 b = *(const ushort8*)(base + 64);
    ushort8 c = *(const ushort8*)(base + 128);
    ushort8 d = *(const ushort8*)(base + 192);
    ushort8 m = umax8(umax8(a, b), umax8(c, d));
#pragma unroll
    for (int k = 0; k < 8; ++k) frow[(cg * 8 + k) * 49 + bin] = m[k];
  }
  __syncthreads();
  const uint4* fsrc = (const uint4*)frow;
  for (int w = t; w < 392; w += 256) fdst[w] = fsrc[w];
}

// ---------------- 8-wave pipelined bf16 GEMM (B^T) — banked (R7/R11) ---------
// per K-tile: {6 G2L(t+2); sched fence; 16 ds_read + 32 MFMA compiler-
// coscheduled; counted vmcnt(6); ONE barrier}.  BM=128, BN=256, BK=64,
// 3 LDS buffers (144 KB), T2 swizzle, XCD-aware block remap, fused bias+ReLU.
__global__ __launch_bounds__(512, 2) void gemm8_bt_relu_k(
    const u16* __restrict__ A, const u16* __restrict__ B,
    const float* __restrict__ bias, u16* __restrict__ C, int N, int K) {
  __shared__ uint4 lds4[9216];  // 3 * (128*64 + 256*64) bf16 = 147456 B
  char* ldsb = (char*)lds4;
  const int t = threadIdx.x;
  const int lane = t & 63, wv = t >> 6;
  const int wm = wv >> 2, wn = wv & 3;

  int bid = blockIdx.x;                      // grid must be exactly 256
  int swz = ((bid & 7) << 5) | (bid >> 3);   // XCD-contiguous remap (bijective)
  const int nb = swz >> 4, mb = swz & 15;
  const int m0 = mb * 128, n0 = nb * 256;

  const u16* __restrict__ Ab = A + (size_t)m0 * K;
  const u16* __restrict__ Bb = B + (size_t)n0 * K;

  const int srow = t >> 3;
  const int sslot = (t & 7) ^ (srow & 7);
  const u16* pA0 = Ab + (size_t)srow * K + sslot * 8;
  const u16* pA1 = pA0 + (size_t)64 * K;
  const u16* pB0 = Bb + (size_t)srow * K + sslot * 8;
  const u16* pB1 = pB0 + (size_t)64 * K;
  const u16* pB2 = pB0 + (size_t)128 * K;
  const u16* pB3 = pB0 + (size_t)192 * K;
  const int dof = t * 16;

#define G2L(src, ldst)                                                        \
  __builtin_amdgcn_global_load_lds(                                          \
      (const __attribute__((address_space(1))) void*)(src),                  \
      (__attribute__((address_space(3))) void*)(ldst), 16, 0, 0)

  const int rA = wm * 64 + (lane & 15);
  const int rB = wn * 64 + (lane & 15);
  const int sl = lane >> 4;
#define LOFF(r, slot) (((r) << 7) + ((((slot) ^ ((r) & 7))) << 4))

  f32x4 acc[4][4] = {};
  bf16x8 afr[4][2], bfr[4][2];

  const int NT = K >> 6;
  {
    char* A0 = ldsb; char* B0 = A0 + 16384;
    char* A1 = ldsb + 49152; char* B1 = A1 + 16384;
    G2L(pA0, A0 + dof); G2L(pA1, A0 + 8192 + dof);
    G2L(pB0, B0 + dof); G2L(pB1, B0 + 8192 + dof);
    G2L(pB2, B0 + 16384 + dof); G2L(pB3, B0 + 24576 + dof);
    G2L(pA0 + 64, A1 + dof); G2L(pA1 + 64, A1 + 8192 + dof);
    G2L(pB0 + 64, B1 + dof); G2L(pB1 + 64, B1 + 8192 + dof);
    G2L(pB2 + 64, B1 + 16384 + dof); G2L(pB3 + 64, B1 + 24576 + dof);
  }
  asm volatile("s_waitcnt vmcnt(6)" ::: "memory");
  __builtin_amdgcn_s_barrier();

  int cb = 0;
  for (int tt = 0; tt < NT; ++tt) {
    const int pb = (cb + 2 >= 3) ? cb - 1 : cb + 2;
    const bool pf = (tt + 2) < NT;
    char* Acur = ldsb + cb * 49152; char* Bcur = Acur + 16384;
    char* Apf  = ldsb + pb * 49152; char* Bpf  = Apf + 16384;
    const int kof = (tt + 2) << 6;

    if (pf) {
      G2L(pA0 + kof, Apf + dof);
      G2L(pA1 + kof, Apf + 8192 + dof);
      G2L(pB0 + kof, Bpf + dof);
      G2L(pB1 + kof, Bpf + 8192 + dof);
      G2L(pB2 + kof, Bpf + 16384 + dof);
      G2L(pB3 + kof, Bpf + 24576 + dof);
    }
    __builtin_amdgcn_sched_barrier(0);
    __builtin_amdgcn_s_setprio(1);
#pragma unroll
    for (int j = 0; j < 4; ++j) {
      bfr[j][0] = *(const bf16x8*)(Bcur + LOFF(rB + j * 16, sl));
      bfr[j][1] = *(const bf16x8*)(Bcur + LOFF(rB + j * 16, 4 + sl));
    }
#pragma unroll
    for (int i = 0; i < 4; ++i) {
      afr[i][0] = *(const bf16x8*)(Acur + LOFF(rA + i * 16, sl));
      afr[i][1] = *(const bf16x8*)(Acur + LOFF(rA + i * 16, 4 + sl));
    }
#pragma unroll
    for (int i = 0; i < 4; ++i)
#pragma unroll
      for (int j = 0; j < 4; ++j) {
        acc[i][j] = __builtin_amdgcn_mfma_f32_16x16x32_bf16(afr[i][0], bfr[j][0], acc[i][j], 0, 0, 0);
        acc[i][j] = __builtin_amdgcn_mfma_f32_16x16x32_bf16(afr[i][1], bfr[j][1], acc[i][j], 0, 0, 0);
      }
    __builtin_amdgcn_s_setprio(0);
    if (pf) {
      asm volatile("s_waitcnt vmcnt(6)" ::: "memory");
    } else if (tt + 1 < NT) {
      asm volatile("s_waitcnt vmcnt(0)" ::: "memory");
    }
    __builtin_amdgcn_s_barrier();
    cb = (cb == 2) ? 0 : cb + 1;
  }
#undef G2L
#undef LOFF

  float bv[4];
#pragma unroll
  for (int j = 0; j < 4; ++j) bv[j] = bias[n0 + wn * 64 + j * 16 + (lane & 15)];
#pragma unroll
  for (int i = 0; i < 4; ++i)
#pragma unroll
    for (int j = 0; j < 4; ++j) {
      int cg = n0 + wn * 64 + j * 16 + (lane & 15);
#pragma unroll
      for (int r = 0; r < 4; ++r) {
        int rg = m0 + wm * 64 + i * 16 + (lane >> 4) * 4 + r;
        float v = fmaxf(acc[i][j][r] + bv[j], 0.f);
        C[(size_t)rg * N + cg] = f2bf(v);
      }
    }
}

// ---------------- cls/bbox heads: 8 ROIs/block, LDS-staged bf16 weights ------
__global__ __launch_bounds__(256) void heads_k(
    const u16* __restrict__ h2, const float* __restrict__ cw,
    const float* __restrict__ cb, const float* __restrict__ bw,
    const float* __restrict__ bb, float* __restrict__ out) {
  __shared__ u16 wl[10][4096];  // 80 KB
  __shared__ float red[4][10];
  const int t = threadIdx.x;
  for (int i4 = t; i4 < 10240; i4 += 256) {
    int j = i4 >> 10, k4 = i4 & 1023;
    float4 v = (j < 2) ? ((const float4*)cw)[j * 1024 + k4]
                       : ((const float4*)bw)[(j - 2) * 1024 + k4];
    uint2 o;
    o.x = (u32)f2bf(v.x) | ((u32)f2bf(v.y) << 16);
    o.y = (u32)f2bf(v.z) | ((u32)f2bf(v.w) << 16);
    *(uint2*)(&wl[j][k4 * 4]) = o;
  }
  __syncthreads();
  const int lane = t & 63, wvi = t >> 6;
  const int m0 = blockIdx.x * 8;
  for (int mi = 0; mi < 8; ++mi) {
    const int m = m0 + mi;
    const u16* hrow = h2 + (size_t)m * 4096;
    float p[10];
#pragma unroll
    for (int j = 0; j < 10; ++j) p[j] = 0.f;
#pragma unroll
    for (int h = 0; h < 2; ++h) {
      const int kc = t + h * 256;
      ushort8 hv = ((const ushort8*)hrow)[kc];
      float hf[8];
#pragma unroll
      for (int e = 0; e < 8; ++e) hf[e] = bf2f(hv[e]);
#pragma unroll
      for (int j = 0; j < 10; ++j) {
        ushort8 wv = *(const ushort8*)(&wl[j][kc * 8]);
#pragma unroll
        for (int e = 0; e < 8; ++e) p[j] = fmaf(hf[e], bf2f(wv[e]), p[j]);
      }
    }
#pragma unroll
    for (int j = 0; j < 10; ++j)
#pragma unroll
      for (int off = 32; off > 0; off >>= 1) p[j] += __shfl_down(p[j], off);
    if (lane == 0) {
#pragma unroll
      for (int j = 0; j < 10; ++j) red[wvi][j] = p[j];
    }
    __syncthreads();
    if (t < 10) {
      float s = red[0][t] + red[1][t] + red[2][t] + red[3][t];
      s += (t < 2) ? cb[t] : bb[t - 2];
      if (t < 2) out[m * 2 + t] = s;
      else out[4000 + m * 8 + (t - 2)] = s;
    }
    __syncthreads();
  }
}

extern "C" void kernel_launch(void* const* d_in, const int* in_sizes, int n_in,
                              void* d_out, int out_size, void* d_ws, size_t ws_size,
                              hipStream_t stream) {
  const float* img    = (const float*)d_in[0];
  const int*   regions= (const int*)d_in[1];
  const float* conv_w = (const float*)d_in[2];
  const float* conv_b = (const float*)d_in[3];
  const float* fc1_w  = (const float*)d_in[4];
  const float* fc1_b  = (const float*)d_in[5];
  const float* fc2_w  = (const float*)d_in[6];
  const float* fc2_b  = (const float*)d_in[7];
  const float* cls_w  = (const float*)d_in[8];
  const float* cls_b  = (const float*)d_in[9];
  const float* bbox_w = (const float*)d_in[10];
  const float* bbox_b = (const float*)d_in[11];
  float* out = (float*)d_out;

  char* ws = (char*)d_ws;
  // layout (bytes), total 105,644,032:
  //   [0, 33554432)          M1 [512][512][64] bf16; dead after roipool2
  //                          -> h1 [0,16M), h2 [16M,32M)
  //   [33554432, 46399488)   feat [2048][3136] bf16
  //   [46399488, 72089600)   w1b  [4096][3136] bf16
  //   [72089600, 105644032)  w2b  [4096][4096] bf16
  u16* M1   = (u16*)(ws);
  u16* h1   = (u16*)(ws);
  u16* h2   = (u16*)(ws + 16777216);
  u16* feat = (u16*)(ws + 33554432);
  u16* w1b  = (u16*)(ws + 46399488);
  u16* w2b  = (u16*)(ws + 72089600);

  conv_vmax_k<<<1536, 512, 0, stream>>>(img, conv_w, conv_b, M1, fc1_w, w1b);
  roipool2_k<<<2560, 256, 0, stream>>>(M1, regions, feat, fc2_w, w2b);
  gemm8_bt_relu_k<<<256, 512, 0, stream>>>(feat, w1b, fc1_b, h1, 4096, 3136);
  gemm8_bt_relu_k<<<256, 512, 0, stream>>>(h1, w2b, fc2_b, h2, 4096, 4096);
  heads_k<<<250, 256, 0, stream>>>(h2, cls_w, cls_b, bbox_w, bbox_b, out);
}